// Round 7
// baseline (72.143 us; speedup 1.0000x reference)
//
#include <hip/hip_runtime.h>
#include <hip/hip_bf16.h>
#include <cstdint>

#define TSEQ 4096
#define NB   4
#define HD   64
#define CEMB 1024
#define NQ   8                 // KV chunks (attention parallelism)
#define KVCH (TSEQ / NQ)       // 512 keys per chunk
#define NTOK (NB * TSEQ)       // 16384
#define SCL  0.18033688011112042f   // 0.125 * log2(e), folded into q at proj

typedef __attribute__((ext_vector_type(8)))  short bfrag;   // 8 bf16 = 4 VGPRs
typedef __attribute__((ext_vector_type(4)))  float f4;
typedef __attribute__((ext_vector_type(16))) float f16v;

#define MFMA16(a, b, c) __builtin_amdgcn_mfma_f32_16x16x32_bf16(a, b, c, 0, 0, 0)
#define MFMA32(a, b, c) __builtin_amdgcn_mfma_f32_32x32x16_bf16(a, b, c, 0, 0, 0)

static __device__ __forceinline__ unsigned short f2bf(float f) {
    __hip_bfloat16 h = __float2bfloat16(f);
    return __builtin_bit_cast(unsigned short, h);
}

static __device__ __forceinline__ float bf2f(unsigned short u) {
    const unsigned v = (unsigned)u << 16;
    return __builtin_bit_cast(float, v);
}

static __device__ __forceinline__ unsigned cvtpk(float lo, float hi) {
    unsigned r;
    asm("v_cvt_pk_bf16_f32 %0, %1, %2" : "=v"(r) : "v"(lo), "v"(hi));
    return r;
}

// ---------------------------------------------------------------------------
// W conversion: Wq|Wk|Wv (each [64][1024] f32) -> wb [192][1024] bf16, once.
// ---------------------------------------------------------------------------
__global__ __launch_bounds__(256) void wcvt_kernel(
    const float* __restrict__ Wq, const float* __restrict__ Wk,
    const float* __restrict__ Wv, unsigned short* __restrict__ wb)
{
    const int row = blockIdx.x;          // 0..191
    const int col = threadIdx.x * 4;     // 0..1020
    const float* W = (row < 64) ? Wq + (size_t)row * CEMB
                   : (row < 128) ? Wk + (size_t)(row - 64) * CEMB
                   : Wv + (size_t)(row - 128) * CEMB;
    const float4 v = *reinterpret_cast<const float4*>(W + col);
    ushort4 o;
    o.x = f2bf(v.x); o.y = f2bf(v.y); o.z = f2bf(v.z); o.w = f2bf(v.w);
    *reinterpret_cast<ushort4*>(wb + (size_t)row * CEMB + col) = o;
}

// ---------------------------------------------------------------------------
// Projection, LDS-staged GEMM with fused f32->bf16 conversion of x.
// Grid 256: block = 64 rows x 192 cols, 4 waves; K-chunks of 64, double-
// buffered XOR-swizzled LDS; T14 early loads; q pre-scaled by SCL.
// ---------------------------------------------------------------------------
__global__ __launch_bounds__(256) void proj_kernel(
    const float* __restrict__ x, const unsigned short* __restrict__ wb,
    unsigned short* __restrict__ qb, unsigned short* __restrict__ kb,
    unsigned short* __restrict__ vt)
{
    __shared__ __attribute__((aligned(16))) unsigned short xs[2][64 * 64];
    __shared__ __attribute__((aligned(16))) unsigned short ws[2][192 * 64];

    const int tid  = threadIdx.x;
    const int w    = tid >> 6;
    const int lane = tid & 63;
    const int ln15 = lane & 15, lg = lane >> 4;
    const int rowg = (w >> 1) * 32;          // 0 / 32 within block
    const int colg = (w & 1) * 96;           // 0 / 96
    const int rowbase = blockIdx.x * 64;

    f4 acc[2][6];
    #pragma unroll
    for (int i = 0; i < 2; ++i)
        #pragma unroll
        for (int j = 0; j < 6; ++j) acc[i][j] = f4{0.f, 0.f, 0.f, 0.f};

    const int xrow = tid >> 2;               // 0..63
    const int xs16 = tid & 3;                // 16-f32 column group
    const int xswz = (xrow & 7) << 4;

    float4 xf[4];
    bfrag  wf[6];
    auto LOADP = [&](int k0) {
        const float* xsrc = x + (size_t)(rowbase + xrow) * CEMB + k0 + xs16 * 16;
        #pragma unroll
        for (int i = 0; i < 4; ++i)
            xf[i] = reinterpret_cast<const float4*>(xsrc)[i];
        #pragma unroll
        for (int i = 0; i < 6; ++i) {
            const int seg = tid + i * 256;           // 0..1535
            const int srow = seg >> 3, sc = seg & 7;
            wf[i] = *reinterpret_cast<const bfrag*>(wb + (size_t)srow * CEMB + k0 + sc * 8);
        }
    };
    auto WRITEP = [&](int c) {
        char* xd = (char*)xs[c];
        char* wd = (char*)ws[c];
        uint4 lo, hi;
        lo.x = cvtpk(xf[0].x, xf[0].y); lo.y = cvtpk(xf[0].z, xf[0].w);
        lo.z = cvtpk(xf[1].x, xf[1].y); lo.w = cvtpk(xf[1].z, xf[1].w);
        hi.x = cvtpk(xf[2].x, xf[2].y); hi.y = cvtpk(xf[2].z, xf[2].w);
        hi.z = cvtpk(xf[3].x, xf[3].y); hi.w = cvtpk(xf[3].z, xf[3].w);
        *reinterpret_cast<uint4*>(xd + xrow * 128 + ((xs16 * 32) ^ xswz)) = lo;
        *reinterpret_cast<uint4*>(xd + xrow * 128 + ((xs16 * 32 + 16) ^ xswz)) = hi;
        #pragma unroll
        for (int i = 0; i < 6; ++i) {
            const int seg = tid + i * 256;
            const int srow = seg >> 3, sc = seg & 7;
            *reinterpret_cast<bfrag*>(wd + srow * 128 + ((sc * 16) ^ ((srow & 7) << 4))) = wf[i];
        }
    };

    LOADP(0);
    WRITEP(0);
    __syncthreads();

    for (int ch = 0; ch < 16; ++ch) {
        const int c = ch & 1;
        if (ch < 15) LOADP((ch + 1) * 64);   // T14: issue early

        const char* xp = (const char*)xs[c];
        const char* wp = (const char*)ws[c];
        __builtin_amdgcn_s_setprio(1);
        #pragma unroll
        for (int ks = 0; ks < 2; ++ks) {
            const int cb = ks * 64 + lg * 16;
            const int r0 = rowg + ln15, r1 = rowg + 16 + ln15;
            const bfrag a0 = *reinterpret_cast<const bfrag*>(xp + r0 * 128 + (cb ^ ((r0 & 7) << 4)));
            const bfrag a1 = *reinterpret_cast<const bfrag*>(xp + r1 * 128 + (cb ^ ((r1 & 7) << 4)));
            #pragma unroll
            for (int ct = 0; ct < 6; ++ct) {
                const int wr = colg + ct * 16 + ln15;
                const bfrag b = *reinterpret_cast<const bfrag*>(wp + wr * 128 + (cb ^ ((wr & 7) << 4)));
                acc[0][ct] = MFMA16(a0, b, acc[0][ct]);
                acc[1][ct] = MFMA16(a1, b, acc[1][ct]);
            }
        }
        __builtin_amdgcn_s_setprio(0);

        if (ch < 15) WRITEP(c ^ 1);
        __syncthreads();
    }

    // D layout: col = lane&15, row = 4*(lane>>4) + reg
    #pragma unroll
    for (int rt = 0; rt < 2; ++rt) {
        #pragma unroll
        for (int ct = 0; ct < 6; ++ct) {
            const int c = colg + ct * 16 + ln15;
            #pragma unroll
            for (int r = 0; r < 4; ++r) {
                const int grow = rowbase + rowg + rt * 16 + 4 * lg + r;
                if (c < 64)        qb[(size_t)grow * HD + c] = f2bf(acc[rt][ct][r] * SCL);
                else if (c < 128)  kb[(size_t)grow * HD + (c - 64)] = f2bf(acc[rt][ct][r]);
                else {
                    const int bbi = grow >> 12, t = grow & 4095;
                    vt[((size_t)(bbi * HD + (c - 128)) << 12) + t] = f2bf(acc[rt][ct][r]);
                }
            }
        }
    }
}

// ---------------------------------------------------------------------------
// Flash attention partials, 32x32 swapped-operand structure.
// Grid (128, NQ): blockIdx.x = 128-q-row group, blockIdx.y = KV chunk
// (KVCH keys, KVCH/64 iters). 4 blocks/CU. Cross-half scalar reductions
// via __shfl_xor(.,32) (proven r4/r5; permlane version had a register-
// coalescing bug: identical "+v" operands may share one VGPR).
// T13 defer-max. Partials written in bf16.
// ---------------------------------------------------------------------------
__global__ __launch_bounds__(256, 4) void attn_kernel(
    const unsigned short* __restrict__ qb, const unsigned short* __restrict__ kb,
    const unsigned short* __restrict__ vt, unsigned short* __restrict__ po,
    float* __restrict__ pm, float* __restrict__ pl)
{
    __shared__ __attribute__((aligned(16))) unsigned short kbuf[2][64 * 64];
    __shared__ __attribute__((aligned(16))) unsigned short vbuf[2][64 * 64];

    const int w    = threadIdx.x >> 6;
    const int lane = threadIdx.x & 63;
    const int ql   = lane & 31;          // this lane's q (column) index
    const int hi   = lane >> 5;
    const int q0   = blockIdx.x * 128 + w * 32;
    const int bb   = blockIdx.x >> 5;    // batch index
    const int kvbase = blockIdx.y * KVCH;

    const size_t kgbase = (size_t)bb * TSEQ * HD;
    const size_t vgbase = (size_t)bb * HD * TSEQ;

    bfrag aq[4];
    #pragma unroll
    for (int s = 0; s < 4; ++s)
        aq[s] = *reinterpret_cast<const bfrag*>(
            qb + (size_t)(q0 + ql) * HD + 16 * s + 8 * hi);

    f16v o0, o1;
    #pragma unroll
    for (int i = 0; i < 16; ++i) { o0[i] = 0.f; o1[i] = 0.f; }
    float m = -__builtin_inff(), lsum = 0.f;

    const int rr  = threadIdx.x >> 3;    // 0..31
    const int rr2 = rr + 32;
    const int seg = threadIdx.x & 7;
    const int dstA = rr  * 128 + ((seg * 16) ^ ((rr  & 7) << 4));
    const int dstB = rr2 * 128 + ((seg * 16) ^ ((rr2 & 7) << 4));

    bfrag st0, st1, st2, st3;
    auto LOADT = [&](int kv0) {
        st0 = *reinterpret_cast<const bfrag*>(kb + kgbase + (size_t)(kv0 + rr)  * HD + seg * 8);
        st1 = *reinterpret_cast<const bfrag*>(kb + kgbase + (size_t)(kv0 + rr2) * HD + seg * 8);
        st2 = *reinterpret_cast<const bfrag*>(vt + vgbase + (size_t)rr  * TSEQ + kv0 + seg * 8);
        st3 = *reinterpret_cast<const bfrag*>(vt + vgbase + (size_t)rr2 * TSEQ + kv0 + seg * 8);
    };
    auto WRITET = [&](int c) {
        char* kd = (char*)kbuf[c];
        char* vd = (char*)vbuf[c];
        *reinterpret_cast<bfrag*>(kd + dstA) = st0;
        *reinterpret_cast<bfrag*>(kd + dstB) = st1;
        *reinterpret_cast<bfrag*>(vd + dstA) = st2;
        *reinterpret_cast<bfrag*>(vd + dstB) = st3;
    };

    auto mkpa = [&](const f16v& p, const int u0) -> bfrag {
        unsigned a0 = cvtpk(p[4 * u0 + 0], p[4 * u0 + 1]);
        unsigned a1 = cvtpk(p[4 * u0 + 2], p[4 * u0 + 3]);
        unsigned b0 = cvtpk(p[4 * u0 + 4], p[4 * u0 + 5]);
        unsigned b1 = cvtpk(p[4 * u0 + 6], p[4 * u0 + 7]);
        asm("v_permlane32_swap_b32 %0, %1" : "+v"(a0), "+v"(b0));
        asm("v_permlane32_swap_b32 %0, %1" : "+v"(a1), "+v"(b1));
        const uint4 u = make_uint4(a0, a1, b0, b1);
        return __builtin_bit_cast(bfrag, u);
    };

    LOADT(kvbase);
    WRITET(0);
    __syncthreads();

    const int swz = (ql & 7) << 4;
    const int NIT = KVCH / 64;

    for (int it = 0; it < NIT; ++it) {
        const int c = it & 1;
        if (it < NIT - 1) LOADT(kvbase + (it + 1) * 64);   // T14: issue early

        const char* kbh = (const char*)kbuf[c];
        const char* vbh = (const char*)vbuf[c];

        f16v s0v, s1v;
        #pragma unroll
        for (int i = 0; i < 16; ++i) { s0v[i] = 0.f; s1v[i] = 0.f; }
        __builtin_amdgcn_s_setprio(1);
        #pragma unroll
        for (int s = 0; s < 4; ++s) {
            const int off = (32 * s + 16 * hi) ^ swz;
            const bfrag k0 = *reinterpret_cast<const bfrag*>(kbh + ql * 128 + off);
            const bfrag k1 = *reinterpret_cast<const bfrag*>(kbh + (ql + 32) * 128 + off);
            s0v = MFMA32(k0, aq[s], s0v);
            s1v = MFMA32(k1, aq[s], s1v);
        }
        __builtin_amdgcn_s_setprio(0);

        // ---- online softmax, lane-local (q = ql) ----
        float b[16];
        #pragma unroll
        for (int i = 0; i < 16; ++i) b[i] = fmaxf(s0v[i], s1v[i]);
        #pragma unroll
        for (int st = 8; st > 0; st >>= 1)
            #pragma unroll
            for (int i = 0; i < 8; ++i) if (i < st) b[i] = fmaxf(b[i], b[i + st]);
        float tmax = b[0];
        tmax = fmaxf(tmax, __shfl_xor(tmax, 32));

        // T13 defer-max: rescale only when the running max actually moves.
        if (!__all(tmax <= m + 8.0f)) {
            const float mn   = fmaxf(m, tmax);
            const float corr = exp2f(m - mn);
            m = mn;
            lsum *= corr;
            #pragma unroll
            for (int i = 0; i < 16; ++i) { o0[i] *= corr; o1[i] *= corr; }
        }
        #pragma unroll
        for (int i = 0; i < 16; ++i) {
            s0v[i] = exp2f(s0v[i] - m);
            s1v[i] = exp2f(s1v[i] - m);
        }
        float a[16];
        #pragma unroll
        for (int i = 0; i < 16; ++i) a[i] = s0v[i] + s1v[i];
        #pragma unroll
        for (int st = 8; st > 0; st >>= 1)
            #pragma unroll
            for (int i = 0; i < 8; ++i) if (i < st) a[i] += a[i + st];
        float sum = a[0];
        sum += __shfl_xor(sum, 32);
        lsum += sum;

        const bfrag pa0 = mkpa(s0v, 0);
        const bfrag pa1 = mkpa(s0v, 2);
        const bfrag pa2 = mkpa(s1v, 0);
        const bfrag pa3 = mkpa(s1v, 2);

        __builtin_amdgcn_s_setprio(1);
        #pragma unroll
        for (int s = 0; s < 4; ++s) {
            const int off = (32 * s + 16 * hi) ^ swz;
            const bfrag v0 = *reinterpret_cast<const bfrag*>(vbh + ql * 128 + off);
            const bfrag v1 = *reinterpret_cast<const bfrag*>(vbh + (ql + 32) * 128 + off);
            const bfrag pa = (s == 0) ? pa0 : (s == 1) ? pa1 : (s == 2) ? pa2 : pa3;
            o0 = MFMA32(v0, pa, o0);
            o1 = MFMA32(v1, pa, o1);
        }
        __builtin_amdgcn_s_setprio(0);

        if (it < NIT - 1) WRITET(c ^ 1);
        __syncthreads();
    }

    // ---- partial write (bf16): lane q = ql, d = 32h + 8u + 4hi + r ----
    const size_t obase = ((size_t)blockIdx.y * NTOK + (q0 + ql)) * HD;
    #pragma unroll
    for (int u = 0; u < 4; ++u) {
        uint2 w0, w1;
        w0.x = cvtpk(o0[4 * u + 0], o0[4 * u + 1]);
        w0.y = cvtpk(o0[4 * u + 2], o0[4 * u + 3]);
        *reinterpret_cast<uint2*>(po + obase + 8 * u + 4 * hi) = w0;
        w1.x = cvtpk(o1[4 * u + 0], o1[4 * u + 1]);
        w1.y = cvtpk(o1[4 * u + 2], o1[4 * u + 3]);
        *reinterpret_cast<uint2*>(po + obase + 32 + 8 * u + 4 * hi) = w1;
    }
    if (hi == 0) {
        pm[blockIdx.y * NTOK + q0 + ql] = m;
        pl[blockIdx.y * NTOK + q0 + ql] = lsum;
    }
}

// ---------------------------------------------------------------------------
// Merge NQ bf16 partials. Thread = (row, 4 consecutive d).
// ---------------------------------------------------------------------------
__global__ __launch_bounds__(256) void merge_kernel(
    const unsigned short* __restrict__ po, const float* __restrict__ pm,
    const float* __restrict__ pl, float* __restrict__ out)
{
    const int t   = blockIdx.x * 256 + threadIdx.x;
    const int row = t >> 4, d0 = (t & 15) * 4;
    float mv[NQ];
    float mx = -__builtin_inff();
    #pragma unroll
    for (int q = 0; q < NQ; ++q) {
        mv[q] = pm[q * NTOK + row];
        mx = fmaxf(mx, mv[q]);
    }
    float lt = 0.f;
    f4 acc = {0.f, 0.f, 0.f, 0.f};
    #pragma unroll
    for (int q = 0; q < NQ; ++q) {
        const float wq = exp2f(mv[q] - mx);
        lt += pl[q * NTOK + row] * wq;
        const ushort4 v = *reinterpret_cast<const ushort4*>(
            po + ((size_t)q * NTOK + row) * HD + d0);
        acc[0] += bf2f(v.x) * wq;
        acc[1] += bf2f(v.y) * wq;
        acc[2] += bf2f(v.z) * wq;
        acc[3] += bf2f(v.w) * wq;
    }
    const float inv = 1.0f / lt;
    f4 r = { acc[0] * inv, acc[1] * inv, acc[2] * inv, acc[3] * inv };
    *reinterpret_cast<f4*>(out + (size_t)row * HD + d0) = r;
}

// ---------------------------------------------------------------------------
extern "C" void kernel_launch(void* const* d_in, const int* in_sizes, int n_in,
                              void* d_out, int out_size, void* d_ws, size_t ws_size,
                              hipStream_t stream) {
    (void)in_sizes; (void)n_in; (void)out_size; (void)ws_size;
    const float* x  = (const float*)d_in[0];
    const float* Wk = (const float*)d_in[1];
    const float* Wq = (const float*)d_in[2];
    const float* Wv = (const float*)d_in[3];

    unsigned short* qb = (unsigned short*)d_ws;            // [16384][64] bf16
    unsigned short* kb = qb + (size_t)NTOK * HD;           // [16384][64] bf16
    unsigned short* vt = kb + (size_t)NTOK * HD;           // [4][64][4096] bf16
    unsigned short* wb = vt + (size_t)NTOK * HD;           // [192][1024] bf16
    unsigned short* po = wb + (size_t)192 * CEMB;          // [NQ][16384][64] bf16
    float* pm = (float*)(po + (size_t)NQ * NTOK * HD);     // [NQ][16384] f32
    float* pl = pm + (size_t)NQ * NTOK;                    // [NQ][16384] f32

    wcvt_kernel<<<192, 256, 0, stream>>>(Wq, Wk, Wv, wb);
    proj_kernel<<<256, 256, 0, stream>>>(x, wb, qb, kb, vt);
    attn_kernel<<<dim3(128, NQ), 256, 0, stream>>>(qb, kb, vt, po, pm, pl);
    merge_kernel<<<NTOK * HD / 1024, 256, 0, stream>>>(po, pm, pl, (float*)d_out);
}